// Round 8
// baseline (975.044 us; speedup 1.0000x reference)
//
// Transformer layer: RMSNorm→QKV→RoPE→SWA-GQA attn→wo+res→RMSNorm→top2 MoE→res
// Round 8: R7 with compile fix (vector-element extraction by value in
// final_add). MoE GEMMs 128^2/BK32/2ph-dbuf + XCD swizzle; GEMM2 K=2048 bf16
// sorted-row output (gate applied); inv[] gather in final_add.
// B=2 S=2048 D=1024 H=16 HK=4 HD=64 WIN=1024 E=8 K=2 DH=2048
#include <hip/hip_runtime.h>
#include <hip/hip_bf16.h>

using bf16 = __hip_bfloat16;
typedef __attribute__((ext_vector_type(8))) short bf16x8;
typedef __attribute__((ext_vector_type(4))) short short4v;
typedef __attribute__((ext_vector_type(4))) float f32x4;

#define DEV static __device__ __forceinline__

DEV float b2f(bf16 v) { return __bfloat162float(v); }
DEV bf16  f2b(float f) { return __float2bfloat16(f); }
DEV short bbits(float f) { bf16 h = __float2bfloat16(f); short u; __builtin_memcpy(&u, &h, 2); return u; }
DEV float sb2f(short s) {
  unsigned u = ((unsigned)(unsigned short)s) << 16;
  float f; __builtin_memcpy(&f, &u, 4); return f;
}

// async global->LDS, 16B per lane, dest = wave-uniform base + lane*16
#define GL2LDS(g, l)                                                        \
  __builtin_amdgcn_global_load_lds(                                         \
      (const __attribute__((address_space(1))) void*)(g),                   \
      (__attribute__((address_space(3))) void*)(l), 16, 0, 0)

// ---------------------------------------------------------------------------
// Transpose + f32->bf16: src [K][N] f32 (batch z, stride K*N) -> dst [N][K] bf16
// ---------------------------------------------------------------------------
__global__ __launch_bounds__(256) void transpose_convert(
    const float* __restrict__ src, bf16* __restrict__ dst, int K, int N) {
  __shared__ float tile[64][65];
  int n0 = blockIdx.x * 64, k0 = blockIdx.y * 64;
  size_t bo = (size_t)blockIdx.z * K * N;
  src += bo; dst += bo;
  int t = threadIdx.x;
  int rr = t >> 4, cc = (t & 15) * 4;
#pragma unroll
  for (int p = 0; p < 4; ++p) {
    int r = rr + p * 16;
    const float4 v = *(const float4*)&src[(size_t)(k0 + r) * N + n0 + cc];
    tile[r][cc] = v.x; tile[r][cc + 1] = v.y; tile[r][cc + 2] = v.z; tile[r][cc + 3] = v.w;
  }
  __syncthreads();
#pragma unroll
  for (int p = 0; p < 4; ++p) {
    int nr = rr + p * 16;
    short4v o;
    o[0] = bbits(tile[cc + 0][nr]);
    o[1] = bbits(tile[cc + 1][nr]);
    o[2] = bbits(tile[cc + 2][nr]);
    o[3] = bbits(tile[cc + 3][nr]);
    *(short4v*)&dst[(size_t)(n0 + nr) * K + k0 + cc] = o;
  }
}

// ---------------------------------------------------------------------------
// RMSNorm: x f32 [rows][1024] -> bf16, one block per row
// ---------------------------------------------------------------------------
__global__ __launch_bounds__(256) void rmsnorm_kernel(
    const float* __restrict__ x, const float* __restrict__ w,
    bf16* __restrict__ o, float eps) {
  int row = blockIdx.x;
  const float* xr = x + (size_t)row * 1024;
  int t = threadIdx.x;
  float4 v = *(const float4*)&xr[t * 4];
  float ss = v.x * v.x + v.y * v.y + v.z * v.z + v.w * v.w;
#pragma unroll
  for (int d = 32; d; d >>= 1) ss += __shfl_down(ss, d);
  __shared__ float red[4];
  if ((t & 63) == 0) red[t >> 6] = ss;
  __syncthreads();
  float sum = red[0] + red[1] + red[2] + red[3];
  float sc = rsqrtf(sum * (1.f / 1024.f) + eps);
  const float4 wv = *(const float4*)&w[t * 4];
  short4v pk;
  pk[0] = bbits(v.x * sc * wv.x);
  pk[1] = bbits(v.y * sc * wv.y);
  pk[2] = bbits(v.z * sc * wv.z);
  pk[3] = bbits(v.w * sc * wv.w);
  *(short4v*)&o[(size_t)row * 1024 + t * 4] = pk;
}

// ---------------------------------------------------------------------------
// RoPE in-place on bf16 [4096][ncols]; pair (2i,2i+1) per head of 64
// ---------------------------------------------------------------------------
__global__ __launch_bounds__(256) void rope_kernel(
    bf16* __restrict__ tbuf, const float* __restrict__ fcos,
    const float* __restrict__ fsin, int ncols, int pshift) {
  int tid = blockIdx.x * 256 + threadIdx.x;
  int row = tid >> pshift;
  int cp = tid & ((1 << pshift) - 1);
  if (row >= 4096) return;
  int i = cp & 31;
  int s = row & 2047;
  bf16* p = tbuf + (size_t)row * ncols + cp * 2;
  float t0 = b2f(p[0]), t1 = b2f(p[1]);
  float c = fcos[s * 32 + i], sn = fsin[s * 32 + i];
  p[0] = f2b(t0 * c - t1 * sn);
  p[1] = f2b(t0 * sn + t1 * c);
}

// ---------------------------------------------------------------------------
// GEMM C[M][N] = A[M][Kd] x Bt[N][Kd]^T   (bf16 in, f32 acc)
// 128x128 tile, BK=32, 4 waves, 2-phase dbuf (R4 structure, 2 blocks/CU),
// XCD-aware tile swizzle (grid x*y divisible by 8 at all call sites).
// MODE 0: bf16 out (q/k)
// MODE 1: f32 out = resid + acc (h)
// MODE 2: MoE GEMM1: A rows gathered via tok, silu, bf16 out rows off+m
// MODE 3: MoE GEMM2: A rows contiguous at off, K=2048, out bf16 sorted rows
//         y2[off+m][1024] = gate * acc
// MODE 4: V proj: write transposed vt[(b*4+kh)*64+d][2048] bf16
// ---------------------------------------------------------------------------
template <int MODE>
__global__ __launch_bounds__(256) void gemm_bt(
    const bf16* __restrict__ A, const bf16* __restrict__ Bt,
    int M, int N, int Kd,
    bf16* __restrict__ outb, float* __restrict__ outf,
    const float* __restrict__ resid,
    const int* __restrict__ counts, const int* __restrict__ offsets,
    const int* __restrict__ tok, const float* __restrict__ gatel) {
  int count = M, off = 0;
  const bf16* Ap = A;
  const bf16* Bp = Bt;
  if (MODE == 2 || MODE == 3) {
    int e = blockIdx.z;
    count = counts[e]; off = offsets[e];
    Bp = Bt + (size_t)e * Kd * N;
    if (MODE == 3) Ap = A + (size_t)off * Kd;
  }
  // XCD swizzle: remap flat bid so each XCD (8-way round-robin) owns a
  // contiguous chunk of tiles.
  int gx = gridDim.x;
  int flat = blockIdx.y * gx + blockIdx.x;
  int cpx = (gx * gridDim.y) >> 3;
  int swz = (flat & 7) * cpx + (flat >> 3);
  int mb = (swz / gx) * 128, nb = (swz % gx) * 128;
  if (mb >= count) return;

  __shared__ __align__(16) bf16 As[2][128 * 32];
  __shared__ __align__(16) bf16 Bs[2][128 * 32];

  int t = threadIdx.x;
  int lane = t & 63, wid = t >> 6;

  // staging: 512 16B-chunks per matrix; chunk p -> row p>>2, slot p&3.
  // slot cs holds global k-chunk cs ^ (row&3) (XOR pre-swizzle on source).
  const bf16* agl[2];
  const bf16* bgl[2];
#pragma unroll
  for (int iss = 0; iss < 2; ++iss) {
    int p = iss * 256 + wid * 64 + lane;
    int row = p >> 2, cs = p & 3;
    int c = cs ^ (row & 3);
    int m = mb + row;
    const bf16* abase;
    if (MODE == 2) {
      int tokid = (m < count) ? tok[off + m] : 0;
      abase = A + (size_t)tokid * Kd;
    } else {
      int mm = (m < count) ? m : 0;
      abase = Ap + (size_t)mm * Kd;
    }
    agl[iss] = abase + c * 8;
    bgl[iss] = Bp + (size_t)(nb + row) * Kd + c * 8;
  }

  int wr = (wid >> 1) * 64, wc = (wid & 1) * 64;
  int lr = lane & 15, lkc = lane >> 4;

  auto stage = [&](int buf, int kt) {
#pragma unroll
    for (int iss = 0; iss < 2; ++iss) {
      GL2LDS(agl[iss] + kt * 32, &As[buf][(iss * 256 + wid * 64) * 8]);
      GL2LDS(bgl[iss] + kt * 32, &Bs[buf][(iss * 256 + wid * 64) * 8]);
    }
  };

  const f32x4 fzero = {0.f, 0.f, 0.f, 0.f};
  f32x4 acc[4][4];
#pragma unroll
  for (int i = 0; i < 4; ++i)
#pragma unroll
    for (int j = 0; j < 4; ++j) acc[i][j] = fzero;

  int nk = Kd >> 5;
  stage(0, 0);
  __syncthreads();
  for (int kt = 0; kt < nk; ++kt) {
    int cur = kt & 1;
    if (kt + 1 < nk) stage(cur ^ 1, kt + 1);
    bf16x8 af[4], bfr[4];
#pragma unroll
    for (int i = 0; i < 4; ++i) {
      int r = wr + i * 16 + lr;
      af[i] = *(const bf16x8*)&As[cur][r * 32 + ((lkc ^ (r & 3)) * 8)];
    }
#pragma unroll
    for (int j = 0; j < 4; ++j) {
      int r = wc + j * 16 + lr;
      bfr[j] = *(const bf16x8*)&Bs[cur][r * 32 + ((lkc ^ (r & 3)) * 8)];
    }
#pragma unroll
    for (int i = 0; i < 4; ++i)
#pragma unroll
      for (int j = 0; j < 4; ++j)
        acc[i][j] = __builtin_amdgcn_mfma_f32_16x16x32_bf16(af[i], bfr[j], acc[i][j], 0, 0, 0);
    __syncthreads();
  }

  int rq = lane >> 4;
#pragma unroll
  for (int i = 0; i < 4; ++i) {
#pragma unroll
    for (int j = 0; j < 4; ++j) {
      if (MODE == 4) {
        int n = nb + wc + j * 16 + lr;       // 0..255
        int kh = n >> 6, d = n & 63;
        int m0 = mb + wr + i * 16 + rq * 4;  // 4 consecutive rows (same b)
        int bb = m0 >> 11, s = m0 & 2047;
        short4v pk;
#pragma unroll
        for (int r = 0; r < 4; ++r) pk[r] = bbits(acc[i][j][r]);
        *(short4v*)&outb[((size_t)((bb * 4 + kh) * 64 + d)) * 2048 + s] = pk;
      } else {
#pragma unroll
        for (int r = 0; r < 4; ++r) {
          int m = mb + wr + i * 16 + rq * 4 + r;
          int n = nb + wc + j * 16 + lr;
          float v = acc[i][j][r];
          if (MODE == 0) {
            outb[(size_t)m * N + n] = f2b(v);
          } else if (MODE == 1) {
            outf[(size_t)m * N + n] = resid[(size_t)m * N + n] + v;
          } else if (MODE == 2) {
            if (m < count) {
              float sg = 1.f / (1.f + expf(-v));
              outb[(size_t)(off + m) * N + n] = f2b(v * sg);
            }
          } else if (MODE == 3) {
            if (m < count) {
              int row = off + m;
              outb[(size_t)row * N + n] = f2b(gatel[row] * v);
            }
          }
        }
      }
    }
  }
}

// ---------------------------------------------------------------------------
// Flash attention, sliding window 1024, GQA 16q/4kv heads, HD=64.
// ---------------------------------------------------------------------------
__global__ __launch_bounds__(256) void attn_kernel(
    const bf16* __restrict__ q, const bf16* __restrict__ kb,
    const bf16* __restrict__ vt, bf16* __restrict__ o) {
  int qb = blockIdx.x, h = blockIdx.y, b = blockIdx.z;
  int kh = h >> 2;
  int t = threadIdx.x;
  int lane = t & 63, wid = t >> 6;
  int lr = lane & 15, lkc = lane >> 4;
  int q0 = qb * 64;
  int qrow = q0 + wid * 16;

  __shared__ __align__(16) bf16 Ks[64 * 64];
  __shared__ __align__(16) bf16 Vs[64 * 64];   // [dim][key]
  __shared__ __align__(16) bf16 Ps[4][16 * 72];

  bf16x8 aq[2];
#pragma unroll
  for (int kk = 0; kk < 2; ++kk)
    aq[kk] = *(const bf16x8*)&q[(size_t)(b * 2048 + qrow + lr) * 1024 + h * 64 + kk * 32 + lkc * 8];

  const f32x4 fzero = {0.f, 0.f, 0.f, 0.f};
  f32x4 oacc[4];
  float mrun[4], lrun[4];
#pragma unroll
  for (int r = 0; r < 4; ++r) { oacc[r] = fzero; mrun[r] = -1e30f; lrun[r] = 0.f; }

  int klo = q0 - 1023; if (klo < 0) klo = 0;
  int tlo = klo >> 6, thi = q0 >> 6;
  int skey = t >> 3;    // 0..31
  int sch = t & 7;      // logical 16B chunk

  for (int kt = tlo; kt <= thi; ++kt) {
    int kbase = kt * 64;
#pragma unroll
    for (int pp = 0; pp < 2; ++pp) {
      int key = skey + pp * 32;
      bf16x8 kv = *(const bf16x8*)&kb[(size_t)(b * 2048 + kbase + key) * 256 + kh * 64 + sch * 8];
      *(bf16x8*)&Ks[key * 64 + ((sch ^ (key & 7)) * 8)] = kv;
      bf16x8 vv = *(const bf16x8*)&vt[((size_t)((b * 4 + kh) * 64 + key)) * 2048 + kbase + sch * 8];
      *(bf16x8*)&Vs[key * 64 + ((sch ^ (key & 7)) * 8)] = vv;
    }
    __syncthreads();

    f32x4 sacc[4];
#pragma unroll
    for (int nt = 0; nt < 4; ++nt) sacc[nt] = fzero;
#pragma unroll
    for (int nt = 0; nt < 4; ++nt)
#pragma unroll
      for (int kk = 0; kk < 2; ++kk) {
        int r = nt * 16 + lr;
        bf16x8 bk = *(const bf16x8*)&Ks[r * 64 + (((kk * 4 + lkc) ^ (r & 7)) * 8)];
        sacc[nt] = __builtin_amdgcn_mfma_f32_16x16x32_bf16(aq[kk], bk, sacc[nt], 0, 0, 0);
      }

    float sval[4][4], mt[4];
    int qg = qrow + lkc * 4;
#pragma unroll
    for (int r = 0; r < 4; ++r) mt[r] = -1e30f;
#pragma unroll
    for (int nt = 0; nt < 4; ++nt) {
      int kkey = kbase + nt * 16 + lr;
#pragma unroll
      for (int r = 0; r < 4; ++r) {
        float s = sacc[nt][r] * 0.125f;
        int qq = qg + r;
        bool valid = (kkey <= qq) && (qq - kkey < 1024);
        s = valid ? s : -1e30f;
        sval[nt][r] = s;
        mt[r] = fmaxf(mt[r], s);
      }
    }
#pragma unroll
    for (int d = 1; d < 16; d <<= 1)
#pragma unroll
      for (int r = 0; r < 4; ++r) mt[r] = fmaxf(mt[r], __shfl_xor(mt[r], d));
    float alpha[4], rs[4];
#pragma unroll
    for (int r = 0; r < 4; ++r) {
      float mn = fmaxf(mrun[r], mt[r]);
      alpha[r] = __expf(mrun[r] - mn);
      mrun[r] = mn;
      rs[r] = 0.f;
    }
#pragma unroll
    for (int nt = 0; nt < 4; ++nt)
#pragma unroll
      for (int r = 0; r < 4; ++r) {
        float pv = __expf(sval[nt][r] - mrun[r]);
        sval[nt][r] = pv;
        rs[r] += pv;
      }
#pragma unroll
    for (int d = 1; d < 16; d <<= 1)
#pragma unroll
      for (int r = 0; r < 4; ++r) rs[r] += __shfl_xor(rs[r], d);
#pragma unroll
    for (int r = 0; r < 4; ++r) lrun[r] = lrun[r] * alpha[r] + rs[r];
#pragma unroll
    for (int dt = 0; dt < 4; ++dt) {
      f32x4 t4 = oacc[dt];
#pragma unroll
      for (int r = 0; r < 4; ++r) t4[r] *= alpha[r];
      oacc[dt] = t4;
    }

    bf16* pw = &Ps[wid][0];
#pragma unroll
    for (int nt = 0; nt < 4; ++nt)
#pragma unroll
      for (int r = 0; r < 4; ++r)
        pw[(lkc * 4 + r) * 72 + nt * 16 + lr] = f2b(sval[nt][r]);
    __syncthreads();

    bf16x8 pa[2];
#pragma unroll
    for (int kk2 = 0; kk2 < 2; ++kk2)
      pa[kk2] = *(const bf16x8*)&pw[lr * 72 + kk2 * 32 + lkc * 8];
#pragma unroll
    for (int dt = 0; dt < 4; ++dt)
#pragma unroll
      for (int kk2 = 0; kk2 < 2; ++kk2) {
        int rrow = dt * 16 + lr;
        bf16x8 bv = *(const bf16x8*)&Vs[rrow * 64 + (((kk2 * 4 + lkc) ^ (rrow & 7)) * 8)];
        oacc[dt] = __builtin_amdgcn_mfma_f32_16x16x32_bf16(pa[kk2], bv, oacc[dt], 0, 0, 0);
      }
    __syncthreads();
  }

#pragma unroll
  for (int dt = 0; dt < 4; ++dt)
#pragma unroll
    for (int r = 0; r < 4; ++r) {
      int qq = qrow + lkc * 4 + r;
      int dd = dt * 16 + lr;
      o[(size_t)(b * 2048 + qq) * 1024 + h * 64 + dd] = f2b(oacc[dt][r] / lrun[r]);
    }
}

// ---------------------------------------------------------------------------
// Router: 4 waves/block, one token per wave. No atomics.
// ---------------------------------------------------------------------------
__global__ __launch_bounds__(256) void router_kernel(
    const float* __restrict__ h, const float* __restrict__ ffnw,
    const float* __restrict__ rw, float* __restrict__ gates,
    int* __restrict__ eidx) {
  int wid = threadIdx.x >> 6, lane = threadIdx.x & 63;
  int row = blockIdx.x * 4 + wid;
  const float* hr = h + (size_t)row * 1024;
  float xs[16];
  float ss = 0.f;
#pragma unroll
  for (int i = 0; i < 16; ++i) { float f = hr[lane + i * 64]; xs[i] = f; ss += f * f; }
#pragma unroll
  for (int d = 32; d; d >>= 1) ss += __shfl_xor(ss, d);
  float sc = rsqrtf(ss * (1.f / 1024.f) + 1e-6f);
  float lg[8];
#pragma unroll
  for (int e = 0; e < 8; ++e) lg[e] = 0.f;
#pragma unroll
  for (int i = 0; i < 16; ++i) {
    int d = lane + i * 64;
    float f = xs[i] * sc * ffnw[d];
    const float* rr = rw + d * 8;
#pragma unroll
    for (int e = 0; e < 8; ++e) lg[e] += f * rr[e];
  }
#pragma unroll
  for (int d = 32; d; d >>= 1)
#pragma unroll
    for (int e = 0; e < 8; ++e) lg[e] += __shfl_xor(lg[e], d);
  if (lane == 0) {
    int e0 = 0; float v0 = lg[0];
#pragma unroll
    for (int e = 1; e < 8; ++e) if (lg[e] > v0) { v0 = lg[e]; e0 = e; }
    int e1 = -1; float v1 = -1e30f;
#pragma unroll
    for (int e = 0; e < 8; ++e) if (e != e0 && lg[e] > v1) { v1 = lg[e]; e1 = e; }
    float r1 = expf(v1 - v0);
    float den = 1.f + r1;
    gates[row * 2] = 1.f / den;
    gates[row * 2 + 1] = r1 / den;
    eidx[row * 2] = e0;
    eidx[row * 2 + 1] = e1;
  }
}

// ---------------------------------------------------------------------------
// moe_setup: 1 block, 1024 threads. LDS histogram -> scan -> fill (+inv map).
// ---------------------------------------------------------------------------
__global__ __launch_bounds__(1024) void moe_setup(
    const int* __restrict__ eidx, const float* __restrict__ gates,
    int* __restrict__ counts, int* __restrict__ offsets,
    int* __restrict__ tok, float* __restrict__ gatel, int* __restrict__ inv) {
  __shared__ int hist[8];
  __shared__ int cur[8];
  int t = threadIdx.x;
  if (t < 8) hist[t] = 0;
  __syncthreads();
  int e[8];
#pragma unroll
  for (int c = 0; c < 8; ++c) {
    e[c] = eidx[c * 1024 + t];
    atomicAdd(&hist[e[c]], 1);
  }
  __syncthreads();
  if (t == 0) {
    int o = 0;
#pragma unroll
    for (int i = 0; i < 8; ++i) {
      offsets[i] = o; cur[i] = o;
      int cnt = hist[i]; counts[i] = cnt; o += cnt;
    }
  }
  __syncthreads();
#pragma unroll
  for (int c = 0; c < 8; ++c) {
    int i = c * 1024 + t;
    int pos = atomicAdd(&cur[e[c]], 1);
    tok[pos] = i >> 1;
    gatel[pos] = gates[i];
    inv[i] = pos;
  }
}

// final: out[t] = h[t] + y2[inv[2t]] + y2[inv[2t+1]]  (y2 rows already gated)
__global__ __launch_bounds__(256) void final_add(
    const float* __restrict__ h, const bf16* __restrict__ y2,
    const int* __restrict__ inv, float* __restrict__ out) {
  int tokid = blockIdx.x;
  int t = threadIdx.x;
  int i0 = inv[tokid * 2], i1 = inv[tokid * 2 + 1];
  size_t base = (size_t)tokid * 1024 + t * 4;
  float4 a = *(const float4*)&h[base];
  short4v p0 = *(const short4v*)&y2[(size_t)i0 * 1024 + t * 4];
  short4v p1 = *(const short4v*)&y2[(size_t)i1 * 1024 + t * 4];
  float4 o;
  o.x = a.x + sb2f(p0[0]) + sb2f(p1[0]);
  o.y = a.y + sb2f(p0[1]) + sb2f(p1[1]);
  o.z = a.z + sb2f(p0[2]) + sb2f(p1[2]);
  o.w = a.w + sb2f(p0[3]) + sb2f(p1[3]);
  *(float4*)&out[base] = o;
}

// ---------------------------------------------------------------------------
extern "C" void kernel_launch(void* const* d_in, const int* in_sizes, int n_in,
                              void* d_out, int out_size, void* d_ws, size_t ws_size,
                              hipStream_t stream) {
  const float* x    = (const float*)d_in[0];
  const float* fcos = (const float*)d_in[1];
  const float* fsin = (const float*)d_in[2];
  const float* attw = (const float*)d_in[3];
  const float* wq   = (const float*)d_in[4];
  const float* wk   = (const float*)d_in[5];
  const float* wv   = (const float*)d_in[6];
  const float* wo   = (const float*)d_in[7];
  const float* ffnw = (const float*)d_in[8];
  const float* rw   = (const float*)d_in[9];
  const float* w1   = (const float*)d_in[10];
  const float* w2   = (const float*)d_in[11];
  float* out = (float*)d_out;

  const int M = 4096;  // B*S tokens
  char* p = (char*)d_ws;
  auto alloc = [&](size_t b) { char* r = p; p += (b + 255) & ~(size_t)255; return r; };

  bf16* hn    = (bf16*)alloc((size_t)M * 1024 * 2);
  bf16* qb    = (bf16*)alloc((size_t)M * 1024 * 2);
  bf16* kbuf  = (bf16*)alloc((size_t)M * 256 * 2);
  bf16* vt    = (bf16*)alloc((size_t)M * 256 * 2);
  bf16* ob    = (bf16*)alloc((size_t)M * 1024 * 2);
  float* hbuf = (float*)alloc((size_t)M * 1024 * 4);
  bf16* fn    = (bf16*)alloc((size_t)M * 1024 * 2);
  bf16* wqt   = (bf16*)alloc((size_t)1024 * 1024 * 2);
  bf16* wkt   = (bf16*)alloc((size_t)256 * 1024 * 2);
  bf16* wvt   = (bf16*)alloc((size_t)256 * 1024 * 2);
  bf16* wot   = (bf16*)alloc((size_t)1024 * 1024 * 2);
  bf16* w1t   = (bf16*)alloc((size_t)8 * 2048 * 1024 * 2);
  bf16* w2t   = (bf16*)alloc((size_t)8 * 1024 * 2048 * 2);
  bf16* act   = (bf16*)alloc((size_t)8192 * 2048 * 2);
  bf16* y2    = (bf16*)alloc((size_t)8192 * 1024 * 2);
  float* gates = (float*)alloc((size_t)M * 2 * 4);
  int* eidx    = (int*)alloc((size_t)M * 2 * 4);
  int* counts  = (int*)alloc(8 * 4);
  int* offsets = (int*)alloc(8 * 4);
  int* tok     = (int*)alloc(8192 * 4);
  int* inv     = (int*)alloc(8192 * 4);
  float* gatel = (float*)alloc(8192 * 4);

  // weight transposes (f32 -> bf16 [N][K])
  transpose_convert<<<dim3(16, 16, 1), 256, 0, stream>>>(wq, wqt, 1024, 1024);
  transpose_convert<<<dim3(4, 16, 1), 256, 0, stream>>>(wk, wkt, 1024, 256);
  transpose_convert<<<dim3(4, 16, 1), 256, 0, stream>>>(wv, wvt, 1024, 256);
  transpose_convert<<<dim3(16, 16, 1), 256, 0, stream>>>(wo, wot, 1024, 1024);
  transpose_convert<<<dim3(32, 16, 8), 256, 0, stream>>>(w1, w1t, 1024, 2048);
  transpose_convert<<<dim3(16, 32, 8), 256, 0, stream>>>(w2, w2t, 2048, 1024);

  rmsnorm_kernel<<<M, 256, 0, stream>>>(x, attw, hn, 1e-5f);

  gemm_bt<0><<<dim3(8, 32, 1), 256, 0, stream>>>(hn, wqt, M, 1024, 1024, qb, nullptr, nullptr,
      nullptr, nullptr, nullptr, nullptr);
  gemm_bt<0><<<dim3(2, 32, 1), 256, 0, stream>>>(hn, wkt, M, 256, 1024, kbuf, nullptr, nullptr,
      nullptr, nullptr, nullptr, nullptr);
  gemm_bt<4><<<dim3(2, 32, 1), 256, 0, stream>>>(hn, wvt, M, 256, 1024, vt, nullptr, nullptr,
      nullptr, nullptr, nullptr, nullptr);

  rope_kernel<<<(M * 512) / 256, 256, 0, stream>>>(qb, fcos, fsin, 1024, 9);
  rope_kernel<<<(M * 128) / 256, 256, 0, stream>>>(kbuf, fcos, fsin, 256, 7);

  attn_kernel<<<dim3(32, 16, 2), 256, 0, stream>>>(qb, kbuf, vt, ob);

  gemm_bt<1><<<dim3(8, 32, 1), 256, 0, stream>>>(ob, wot, M, 1024, 1024, nullptr, hbuf, x,
      nullptr, nullptr, nullptr, nullptr);

  rmsnorm_kernel<<<M, 256, 0, stream>>>(hbuf, ffnw, fn, 1e-6f);

  router_kernel<<<M / 4, 256, 0, stream>>>(hbuf, ffnw, rw, gates, eidx);
  moe_setup<<<1, 1024, 0, stream>>>(eidx, gates, counts, offsets, tok, gatel, inv);

  // MoE GEMM1: act[pos][2048] = silu(fn[tok[pos]] @ w1[e]); grid y=64 covers
  // worst-case 8192 rows on one expert.
  gemm_bt<2><<<dim3(16, 64, 8), 256, 0, stream>>>(fn, w1t, M, 2048, 1024, act, nullptr, nullptr,
      counts, offsets, tok, nullptr);
  // MoE GEMM2: y2[pos][1024] = gate[pos] * (act[pos] @ w2[e]), K=2048
  gemm_bt<3><<<dim3(8, 64, 8), 256, 0, stream>>>(act, w2t, M, 1024, 2048, y2, nullptr, nullptr,
      counts, offsets, tok, gatel);

  final_add<<<M, 256, 0, stream>>>(hbuf, y2, inv, out);
}

// Round 9
// 395.288 us; speedup vs baseline: 2.4667x; 2.4667x over previous
//
// Transformer layer: RMSNorm→QKV→RoPE→SWA-GQA attn→wo+res→RMSNorm→top2 MoE→res
// Round 9: R8 minus the MoE-grid XCD swizzle (it concentrated all working
// tiles onto one XCD because surviving blocks were flat%8==0). Swizzle kept
// only for dense modes where every block does work.
// B=2 S=2048 D=1024 H=16 HK=4 HD=64 WIN=1024 E=8 K=2 DH=2048
#include <hip/hip_runtime.h>
#include <hip/hip_bf16.h>

using bf16 = __hip_bfloat16;
typedef __attribute__((ext_vector_type(8))) short bf16x8;
typedef __attribute__((ext_vector_type(4))) short short4v;
typedef __attribute__((ext_vector_type(4))) float f32x4;

#define DEV static __device__ __forceinline__

DEV float b2f(bf16 v) { return __bfloat162float(v); }
DEV bf16  f2b(float f) { return __float2bfloat16(f); }
DEV short bbits(float f) { bf16 h = __float2bfloat16(f); short u; __builtin_memcpy(&u, &h, 2); return u; }
DEV float sb2f(short s) {
  unsigned u = ((unsigned)(unsigned short)s) << 16;
  float f; __builtin_memcpy(&f, &u, 4); return f;
}

// async global->LDS, 16B per lane, dest = wave-uniform base + lane*16
#define GL2LDS(g, l)                                                        \
  __builtin_amdgcn_global_load_lds(                                         \
      (const __attribute__((address_space(1))) void*)(g),                   \
      (__attribute__((address_space(3))) void*)(l), 16, 0, 0)

// ---------------------------------------------------------------------------
// Transpose + f32->bf16: src [K][N] f32 (batch z, stride K*N) -> dst [N][K] bf16
// ---------------------------------------------------------------------------
__global__ __launch_bounds__(256) void transpose_convert(
    const float* __restrict__ src, bf16* __restrict__ dst, int K, int N) {
  __shared__ float tile[64][65];
  int n0 = blockIdx.x * 64, k0 = blockIdx.y * 64;
  size_t bo = (size_t)blockIdx.z * K * N;
  src += bo; dst += bo;
  int t = threadIdx.x;
  int rr = t >> 4, cc = (t & 15) * 4;
#pragma unroll
  for (int p = 0; p < 4; ++p) {
    int r = rr + p * 16;
    const float4 v = *(const float4*)&src[(size_t)(k0 + r) * N + n0 + cc];
    tile[r][cc] = v.x; tile[r][cc + 1] = v.y; tile[r][cc + 2] = v.z; tile[r][cc + 3] = v.w;
  }
  __syncthreads();
#pragma unroll
  for (int p = 0; p < 4; ++p) {
    int nr = rr + p * 16;
    short4v o;
    o[0] = bbits(tile[cc + 0][nr]);
    o[1] = bbits(tile[cc + 1][nr]);
    o[2] = bbits(tile[cc + 2][nr]);
    o[3] = bbits(tile[cc + 3][nr]);
    *(short4v*)&dst[(size_t)(n0 + nr) * K + k0 + cc] = o;
  }
}

// ---------------------------------------------------------------------------
// RMSNorm: x f32 [rows][1024] -> bf16, one block per row
// ---------------------------------------------------------------------------
__global__ __launch_bounds__(256) void rmsnorm_kernel(
    const float* __restrict__ x, const float* __restrict__ w,
    bf16* __restrict__ o, float eps) {
  int row = blockIdx.x;
  const float* xr = x + (size_t)row * 1024;
  int t = threadIdx.x;
  float4 v = *(const float4*)&xr[t * 4];
  float ss = v.x * v.x + v.y * v.y + v.z * v.z + v.w * v.w;
#pragma unroll
  for (int d = 32; d; d >>= 1) ss += __shfl_down(ss, d);
  __shared__ float red[4];
  if ((t & 63) == 0) red[t >> 6] = ss;
  __syncthreads();
  float sum = red[0] + red[1] + red[2] + red[3];
  float sc = rsqrtf(sum * (1.f / 1024.f) + eps);
  const float4 wv = *(const float4*)&w[t * 4];
  short4v pk;
  pk[0] = bbits(v.x * sc * wv.x);
  pk[1] = bbits(v.y * sc * wv.y);
  pk[2] = bbits(v.z * sc * wv.z);
  pk[3] = bbits(v.w * sc * wv.w);
  *(short4v*)&o[(size_t)row * 1024 + t * 4] = pk;
}

// ---------------------------------------------------------------------------
// RoPE in-place on bf16 [4096][ncols]; pair (2i,2i+1) per head of 64
// ---------------------------------------------------------------------------
__global__ __launch_bounds__(256) void rope_kernel(
    bf16* __restrict__ tbuf, const float* __restrict__ fcos,
    const float* __restrict__ fsin, int ncols, int pshift) {
  int tid = blockIdx.x * 256 + threadIdx.x;
  int row = tid >> pshift;
  int cp = tid & ((1 << pshift) - 1);
  if (row >= 4096) return;
  int i = cp & 31;
  int s = row & 2047;
  bf16* p = tbuf + (size_t)row * ncols + cp * 2;
  float t0 = b2f(p[0]), t1 = b2f(p[1]);
  float c = fcos[s * 32 + i], sn = fsin[s * 32 + i];
  p[0] = f2b(t0 * c - t1 * sn);
  p[1] = f2b(t0 * sn + t1 * c);
}

// ---------------------------------------------------------------------------
// GEMM C[M][N] = A[M][Kd] x Bt[N][Kd]^T   (bf16 in, f32 acc)
// 128x128 tile, BK=32, 4 waves, 2-phase dbuf (R4 structure, 2 blocks/CU).
// XCD swizzle ONLY for dense modes (every block works); MoE modes use the
// identity mapping so working blocks stay round-robin across XCDs.
// MODE 0: bf16 out (q/k)
// MODE 1: f32 out = resid + acc (h)
// MODE 2: MoE GEMM1: A rows gathered via tok, silu, bf16 out rows off+m
// MODE 3: MoE GEMM2: A rows contiguous at off, K=2048, y2[off+m] = gate*acc
// MODE 4: V proj: write transposed vt[(b*4+kh)*64+d][2048] bf16
// ---------------------------------------------------------------------------
template <int MODE>
__global__ __launch_bounds__(256) void gemm_bt(
    const bf16* __restrict__ A, const bf16* __restrict__ Bt,
    int M, int N, int Kd,
    bf16* __restrict__ outb, float* __restrict__ outf,
    const float* __restrict__ resid,
    const int* __restrict__ counts, const int* __restrict__ offsets,
    const int* __restrict__ tok, const float* __restrict__ gatel) {
  int count = M, off = 0;
  const bf16* Ap = A;
  const bf16* Bp = Bt;
  if (MODE == 2 || MODE == 3) {
    int e = blockIdx.z;
    count = counts[e]; off = offsets[e];
    Bp = Bt + (size_t)e * Kd * N;
    if (MODE == 3) Ap = A + (size_t)off * Kd;
  }
  int mb, nb;
  if (MODE == 2 || MODE == 3) {
    mb = blockIdx.y * 128; nb = blockIdx.x * 128;
  } else {
    int gx = gridDim.x;
    int flat = blockIdx.y * gx + blockIdx.x;
    int cpx = (gx * gridDim.y) >> 3;
    int swz = (flat & 7) * cpx + (flat >> 3);
    mb = (swz / gx) * 128; nb = (swz % gx) * 128;
  }
  if (mb >= count) return;

  __shared__ __align__(16) bf16 As[2][128 * 32];
  __shared__ __align__(16) bf16 Bs[2][128 * 32];

  int t = threadIdx.x;
  int lane = t & 63, wid = t >> 6;

  // staging: 512 16B-chunks per matrix; chunk p -> row p>>2, slot p&3.
  // slot cs holds global k-chunk cs ^ (row&3) (XOR pre-swizzle on source).
  const bf16* agl[2];
  const bf16* bgl[2];
#pragma unroll
  for (int iss = 0; iss < 2; ++iss) {
    int p = iss * 256 + wid * 64 + lane;
    int row = p >> 2, cs = p & 3;
    int c = cs ^ (row & 3);
    int m = mb + row;
    const bf16* abase;
    if (MODE == 2) {
      int tokid = (m < count) ? tok[off + m] : 0;
      abase = A + (size_t)tokid * Kd;
    } else {
      int mm = (m < count) ? m : 0;
      abase = Ap + (size_t)mm * Kd;
    }
    agl[iss] = abase + c * 8;
    bgl[iss] = Bp + (size_t)(nb + row) * Kd + c * 8;
  }

  int wr = (wid >> 1) * 64, wc = (wid & 1) * 64;
  int lr = lane & 15, lkc = lane >> 4;

  auto stage = [&](int buf, int kt) {
#pragma unroll
    for (int iss = 0; iss < 2; ++iss) {
      GL2LDS(agl[iss] + kt * 32, &As[buf][(iss * 256 + wid * 64) * 8]);
      GL2LDS(bgl[iss] + kt * 32, &Bs[buf][(iss * 256 + wid * 64) * 8]);
    }
  };

  const f32x4 fzero = {0.f, 0.f, 0.f, 0.f};
  f32x4 acc[4][4];
#pragma unroll
  for (int i = 0; i < 4; ++i)
#pragma unroll
    for (int j = 0; j < 4; ++j) acc[i][j] = fzero;

  int nk = Kd >> 5;
  stage(0, 0);
  __syncthreads();
  for (int kt = 0; kt < nk; ++kt) {
    int cur = kt & 1;
    if (kt + 1 < nk) stage(cur ^ 1, kt + 1);
    bf16x8 af[4], bfr[4];
#pragma unroll
    for (int i = 0; i < 4; ++i) {
      int r = wr + i * 16 + lr;
      af[i] = *(const bf16x8*)&As[cur][r * 32 + ((lkc ^ (r & 3)) * 8)];
    }
#pragma unroll
    for (int j = 0; j < 4; ++j) {
      int r = wc + j * 16 + lr;
      bfr[j] = *(const bf16x8*)&Bs[cur][r * 32 + ((lkc ^ (r & 3)) * 8)];
    }
#pragma unroll
    for (int i = 0; i < 4; ++i)
#pragma unroll
      for (int j = 0; j < 4; ++j)
        acc[i][j] = __builtin_amdgcn_mfma_f32_16x16x32_bf16(af[i], bfr[j], acc[i][j], 0, 0, 0);
    __syncthreads();
  }

  int rq = lane >> 4;
#pragma unroll
  for (int i = 0; i < 4; ++i) {
#pragma unroll
    for (int j = 0; j < 4; ++j) {
      if (MODE == 4) {
        int n = nb + wc + j * 16 + lr;       // 0..255
        int kh = n >> 6, d = n & 63;
        int m0 = mb + wr + i * 16 + rq * 4;  // 4 consecutive rows (same b)
        int bb = m0 >> 11, s = m0 & 2047;
        short4v pk;
#pragma unroll
        for (int r = 0; r < 4; ++r) pk[r] = bbits(acc[i][j][r]);
        *(short4v*)&outb[((size_t)((bb * 4 + kh) * 64 + d)) * 2048 + s] = pk;
      } else {
#pragma unroll
        for (int r = 0; r < 4; ++r) {
          int m = mb + wr + i * 16 + rq * 4 + r;
          int n = nb + wc + j * 16 + lr;
          float v = acc[i][j][r];
          if (MODE == 0) {
            outb[(size_t)m * N + n] = f2b(v);
          } else if (MODE == 1) {
            outf[(size_t)m * N + n] = resid[(size_t)m * N + n] + v;
          } else if (MODE == 2) {
            if (m < count) {
              float sg = 1.f / (1.f + expf(-v));
              outb[(size_t)(off + m) * N + n] = f2b(v * sg);
            }
          } else if (MODE == 3) {
            if (m < count) {
              int row = off + m;
              outb[(size_t)row * N + n] = f2b(gatel[row] * v);
            }
          }
        }
      }
    }
  }
}

// ---------------------------------------------------------------------------
// Flash attention, sliding window 1024, GQA 16q/4kv heads, HD=64.
// ---------------------------------------------------------------------------
__global__ __launch_bounds__(256) void attn_kernel(
    const bf16* __restrict__ q, const bf16* __restrict__ kb,
    const bf16* __restrict__ vt, bf16* __restrict__ o) {
  int qb = blockIdx.x, h = blockIdx.y, b = blockIdx.z;
  int kh = h >> 2;
  int t = threadIdx.x;
  int lane = t & 63, wid = t >> 6;
  int lr = lane & 15, lkc = lane >> 4;
  int q0 = qb * 64;
  int qrow = q0 + wid * 16;

  __shared__ __align__(16) bf16 Ks[64 * 64];
  __shared__ __align__(16) bf16 Vs[64 * 64];   // [dim][key]
  __shared__ __align__(16) bf16 Ps[4][16 * 72];

  bf16x8 aq[2];
#pragma unroll
  for (int kk = 0; kk < 2; ++kk)
    aq[kk] = *(const bf16x8*)&q[(size_t)(b * 2048 + qrow + lr) * 1024 + h * 64 + kk * 32 + lkc * 8];

  const f32x4 fzero = {0.f, 0.f, 0.f, 0.f};
  f32x4 oacc[4];
  float mrun[4], lrun[4];
#pragma unroll
  for (int r = 0; r < 4; ++r) { oacc[r] = fzero; mrun[r] = -1e30f; lrun[r] = 0.f; }

  int klo = q0 - 1023; if (klo < 0) klo = 0;
  int tlo = klo >> 6, thi = q0 >> 6;
  int skey = t >> 3;    // 0..31
  int sch = t & 7;      // logical 16B chunk

  for (int kt = tlo; kt <= thi; ++kt) {
    int kbase = kt * 64;
#pragma unroll
    for (int pp = 0; pp < 2; ++pp) {
      int key = skey + pp * 32;
      bf16x8 kv = *(const bf16x8*)&kb[(size_t)(b * 2048 + kbase + key) * 256 + kh * 64 + sch * 8];
      *(bf16x8*)&Ks[key * 64 + ((sch ^ (key & 7)) * 8)] = kv;
      bf16x8 vv = *(const bf16x8*)&vt[((size_t)((b * 4 + kh) * 64 + key)) * 2048 + kbase + sch * 8];
      *(bf16x8*)&Vs[key * 64 + ((sch ^ (key & 7)) * 8)] = vv;
    }
    __syncthreads();

    f32x4 sacc[4];
#pragma unroll
    for (int nt = 0; nt < 4; ++nt) sacc[nt] = fzero;
#pragma unroll
    for (int nt = 0; nt < 4; ++nt)
#pragma unroll
      for (int kk = 0; kk < 2; ++kk) {
        int r = nt * 16 + lr;
        bf16x8 bk = *(const bf16x8*)&Ks[r * 64 + (((kk * 4 + lkc) ^ (r & 7)) * 8)];
        sacc[nt] = __builtin_amdgcn_mfma_f32_16x16x32_bf16(aq[kk], bk, sacc[nt], 0, 0, 0);
      }

    float sval[4][4], mt[4];
    int qg = qrow + lkc * 4;
#pragma unroll
    for (int r = 0; r < 4; ++r) mt[r] = -1e30f;
#pragma unroll
    for (int nt = 0; nt < 4; ++nt) {
      int kkey = kbase + nt * 16 + lr;
#pragma unroll
      for (int r = 0; r < 4; ++r) {
        float s = sacc[nt][r] * 0.125f;
        int qq = qg + r;
        bool valid = (kkey <= qq) && (qq - kkey < 1024);
        s = valid ? s : -1e30f;
        sval[nt][r] = s;
        mt[r] = fmaxf(mt[r], s);
      }
    }
#pragma unroll
    for (int d = 1; d < 16; d <<= 1)
#pragma unroll
      for (int r = 0; r < 4; ++r) mt[r] = fmaxf(mt[r], __shfl_xor(mt[r], d));
    float alpha[4], rs[4];
#pragma unroll
    for (int r = 0; r < 4; ++r) {
      float mn = fmaxf(mrun[r], mt[r]);
      alpha[r] = __expf(mrun[r] - mn);
      mrun[r] = mn;
      rs[r] = 0.f;
    }
#pragma unroll
    for (int nt = 0; nt < 4; ++nt)
#pragma unroll
      for (int r = 0; r < 4; ++r) {
        float pv = __expf(sval[nt][r] - mrun[r]);
        sval[nt][r] = pv;
        rs[r] += pv;
      }
#pragma unroll
    for (int d = 1; d < 16; d <<= 1)
#pragma unroll
      for (int r = 0; r < 4; ++r) rs[r] += __shfl_xor(rs[r], d);
#pragma unroll
    for (int r = 0; r < 4; ++r) lrun[r] = lrun[r] * alpha[r] + rs[r];
#pragma unroll
    for (int dt = 0; dt < 4; ++dt) {
      f32x4 t4 = oacc[dt];
#pragma unroll
      for (int r = 0; r < 4; ++r) t4[r] *= alpha[r];
      oacc[dt] = t4;
    }

    bf16* pw = &Ps[wid][0];
#pragma unroll
    for (int nt = 0; nt < 4; ++nt)
#pragma unroll
      for (int r = 0; r < 4; ++r)
        pw[(lkc * 4 + r) * 72 + nt * 16 + lr] = f2b(sval[nt][r]);
    __syncthreads();

    bf16x8 pa[2];
#pragma unroll
    for (int kk2 = 0; kk2 < 2; ++kk2)
      pa[kk2] = *(const bf16x8*)&pw[lr * 72 + kk2 * 32 + lkc * 8];
#pragma unroll
    for (int dt = 0; dt < 4; ++dt)
#pragma unroll
      for (int kk2 = 0; kk2 < 2; ++kk2) {
        int rrow = dt * 16 + lr;
        bf16x8 bv = *(const bf16x8*)&Vs[rrow * 64 + (((kk2 * 4 + lkc) ^ (rrow & 7)) * 8)];
        oacc[dt] = __builtin_amdgcn_mfma_f32_16x16x32_bf16(pa[kk2], bv, oacc[dt], 0, 0, 0);
      }
    __syncthreads();
  }

#pragma unroll
  for (int dt = 0; dt < 4; ++dt)
#pragma unroll
    for (int r = 0; r < 4; ++r) {
      int qq = qrow + lkc * 4 + r;
      int dd = dt * 16 + lr;
      o[(size_t)(b * 2048 + qq) * 1024 + h * 64 + dd] = f2b(oacc[dt][r] / lrun[r]);
    }
}

// ---------------------------------------------------------------------------
// Router: 4 waves/block, one token per wave. No atomics.
// ---------------------------------------------------------------------------
__global__ __launch_bounds__(256) void router_kernel(
    const float* __restrict__ h, const float* __restrict__ ffnw,
    const float* __restrict__ rw, float* __restrict__ gates,
    int* __restrict__ eidx) {
  int wid = threadIdx.x >> 6, lane = threadIdx.x & 63;
  int row = blockIdx.x * 4 + wid;
  const float* hr = h + (size_t)row * 1024;
  float xs[16];
  float ss = 0.f;
#pragma unroll
  for (int i = 0; i < 16; ++i) { float f = hr[lane + i * 64]; xs[i] = f; ss += f * f; }
#pragma unroll
  for (int d = 32; d; d >>= 1) ss += __shfl_xor(ss, d);
  float sc = rsqrtf(ss * (1.f / 1024.f) + 1e-6f);
  float lg[8];
#pragma unroll
  for (int e = 0; e < 8; ++e) lg[e] = 0.f;
#pragma unroll
  for (int i = 0; i < 16; ++i) {
    int d = lane + i * 64;
    float f = xs[i] * sc * ffnw[d];
    const float* rr = rw + d * 8;
#pragma unroll
    for (int e = 0; e < 8; ++e) lg[e] += f * rr[e];
  }
#pragma unroll
  for (int d = 32; d; d >>= 1)
#pragma unroll
    for (int e = 0; e < 8; ++e) lg[e] += __shfl_xor(lg[e], d);
  if (lane == 0) {
    int e0 = 0; float v0 = lg[0];
#pragma unroll
    for (int e = 1; e < 8; ++e) if (lg[e] > v0) { v0 = lg[e]; e0 = e; }
    int e1 = -1; float v1 = -1e30f;
#pragma unroll
    for (int e = 0; e < 8; ++e) if (e != e0 && lg[e] > v1) { v1 = lg[e]; e1 = e; }
    float r1 = expf(v1 - v0);
    float den = 1.f + r1;
    gates[row * 2] = 1.f / den;
    gates[row * 2 + 1] = r1 / den;
    eidx[row * 2] = e0;
    eidx[row * 2 + 1] = e1;
  }
}

// ---------------------------------------------------------------------------
// moe_setup: 1 block, 1024 threads. LDS histogram -> scan -> fill (+inv map).
// ---------------------------------------------------------------------------
__global__ __launch_bounds__(1024) void moe_setup(
    const int* __restrict__ eidx, const float* __restrict__ gates,
    int* __restrict__ counts, int* __restrict__ offsets,
    int* __restrict__ tok, float* __restrict__ gatel, int* __restrict__ inv) {
  __shared__ int hist[8];
  __shared__ int cur[8];
  int t = threadIdx.x;
  if (t < 8) hist[t] = 0;
  __syncthreads();
  int e[8];
#pragma unroll
  for (int c = 0; c < 8; ++c) {
    e[c] = eidx[c * 1024 + t];
    atomicAdd(&hist[e[c]], 1);
  }
  __syncthreads();
  if (t == 0) {
    int o = 0;
#pragma unroll
    for (int i = 0; i < 8; ++i) {
      offsets[i] = o; cur[i] = o;
      int cnt = hist[i]; counts[i] = cnt; o += cnt;
    }
  }
  __syncthreads();
#pragma unroll
  for (int c = 0; c < 8; ++c) {
    int i = c * 1024 + t;
    int pos = atomicAdd(&cur[e[c]], 1);
    tok[pos] = i >> 1;
    gatel[pos] = gates[i];
    inv[i] = pos;
  }
}

// final: out[t] = h[t] + y2[inv[2t]] + y2[inv[2t+1]]  (y2 rows already gated)
__global__ __launch_bounds__(256) void final_add(
    const float* __restrict__ h, const bf16* __restrict__ y2,
    const int* __restrict__ inv, float* __restrict__ out) {
  int tokid = blockIdx.x;
  int t = threadIdx.x;
  int i0 = inv[tokid * 2], i1 = inv[tokid * 2 + 1];
  size_t base = (size_t)tokid * 1024 + t * 4;
  float4 a = *(const float4*)&h[base];
  short4v p0 = *(const short4v*)&y2[(size_t)i0 * 1024 + t * 4];
  short4v p1 = *(const short4v*)&y2[(size_t)i1 * 1024 + t * 4];
  float4 o;
  o.x = a.x + sb2f(p0[0]) + sb2f(p1[0]);
  o.y = a.y + sb2f(p0[1]) + sb2f(p1[1]);
  o.z = a.z + sb2f(p0[2]) + sb2f(p1[2]);
  o.w = a.w + sb2f(p0[3]) + sb2f(p1[3]);
  *(float4*)&out[base] = o;
}

// ---------------------------------------------------------------------------
extern "C" void kernel_launch(void* const* d_in, const int* in_sizes, int n_in,
                              void* d_out, int out_size, void* d_ws, size_t ws_size,
                              hipStream_t stream) {
  const float* x    = (const float*)d_in[0];
  const float* fcos = (const float*)d_in[1];
  const float* fsin = (const float*)d_in[2];
  const float* attw = (const float*)d_in[3];
  const float* wq   = (const float*)d_in[4];
  const float* wk   = (const float*)d_in[5];
  const float* wv   = (const float*)d_in[6];
  const float* wo   = (const float*)d_in[7];
  const float* ffnw = (const float*)d_in[8];
  const float* rw   = (const float*)d_in[9];
  const float* w1   = (const float*)d_in[10];
  const float* w2   = (const float*)d_in[11];
  float* out = (float*)d_out;

  const int M = 4096;  // B*S tokens
  char* p = (char*)d_ws;
  auto alloc = [&](size_t b) { char* r = p; p += (b + 255) & ~(size_t)255; return r; };

  bf16* hn    = (bf16*)alloc((size_t)M * 1024 * 2);
  bf16* qb    = (bf16*)alloc((size_t)M * 1024 * 2);
  bf16* kbuf  = (bf16*)alloc((size_t)M * 256 * 2);
  bf16* vt    = (bf16*)alloc((size_t)M * 256 * 2);
  bf16* ob    = (bf16*)alloc((size_t)M * 1024 * 2);
  float* hbuf = (float*)alloc((size_t)M * 1024 * 4);
  bf16* fn    = (bf16*)alloc((size_t)M * 1024 * 2);
  bf16* wqt   = (bf16*)alloc((size_t)1024 * 1024 * 2);
  bf16* wkt   = (bf16*)alloc((size_t)256 * 1024 * 2);
  bf16* wvt   = (bf16*)alloc((size_t)256 * 1024 * 2);
  bf16* wot   = (bf16*)alloc((size_t)1024 * 1024 * 2);
  bf16* w1t   = (bf16*)alloc((size_t)8 * 2048 * 1024 * 2);
  bf16* w2t   = (bf16*)alloc((size_t)8 * 1024 * 2048 * 2);
  bf16* act   = (bf16*)alloc((size_t)8192 * 2048 * 2);
  bf16* y2    = (bf16*)alloc((size_t)8192 * 1024 * 2);
  float* gates = (float*)alloc((size_t)M * 2 * 4);
  int* eidx    = (int*)alloc((size_t)M * 2 * 4);
  int* counts  = (int*)alloc(8 * 4);
  int* offsets = (int*)alloc(8 * 4);
  int* tok     = (int*)alloc(8192 * 4);
  int* inv     = (int*)alloc(8192 * 4);
  float* gatel = (float*)alloc(8192 * 4);

  // weight transposes (f32 -> bf16 [N][K])
  transpose_convert<<<dim3(16, 16, 1), 256, 0, stream>>>(wq, wqt, 1024, 1024);
  transpose_convert<<<dim3(4, 16, 1), 256, 0, stream>>>(wk, wkt, 1024, 256);
  transpose_convert<<<dim3(4, 16, 1), 256, 0, stream>>>(wv, wvt, 1024, 256);
  transpose_convert<<<dim3(16, 16, 1), 256, 0, stream>>>(wo, wot, 1024, 1024);
  transpose_convert<<<dim3(32, 16, 8), 256, 0, stream>>>(w1, w1t, 1024, 2048);
  transpose_convert<<<dim3(16, 32, 8), 256, 0, stream>>>(w2, w2t, 2048, 1024);

  rmsnorm_kernel<<<M, 256, 0, stream>>>(x, attw, hn, 1e-5f);

  gemm_bt<0><<<dim3(8, 32, 1), 256, 0, stream>>>(hn, wqt, M, 1024, 1024, qb, nullptr, nullptr,
      nullptr, nullptr, nullptr, nullptr);
  gemm_bt<0><<<dim3(2, 32, 1), 256, 0, stream>>>(hn, wkt, M, 256, 1024, kbuf, nullptr, nullptr,
      nullptr, nullptr, nullptr, nullptr);
  gemm_bt<4><<<dim3(2, 32, 1), 256, 0, stream>>>(hn, wvt, M, 256, 1024, vt, nullptr, nullptr,
      nullptr, nullptr, nullptr, nullptr);

  rope_kernel<<<(M * 512) / 256, 256, 0, stream>>>(qb, fcos, fsin, 1024, 9);
  rope_kernel<<<(M * 128) / 256, 256, 0, stream>>>(kbuf, fcos, fsin, 256, 7);

  attn_kernel<<<dim3(32, 16, 2), 256, 0, stream>>>(qb, kbuf, vt, ob);

  gemm_bt<1><<<dim3(8, 32, 1), 256, 0, stream>>>(ob, wot, M, 1024, 1024, nullptr, hbuf, x,
      nullptr, nullptr, nullptr, nullptr);

  rmsnorm_kernel<<<M, 256, 0, stream>>>(hbuf, ffnw, fn, 1e-6f);

  router_kernel<<<M / 4, 256, 0, stream>>>(hbuf, ffnw, rw, gates, eidx);
  moe_setup<<<1, 1024, 0, stream>>>(eidx, gates, counts, offsets, tok, gatel, inv);

  // MoE GEMM1: act[pos][2048] = silu(fn[tok[pos]] @ w1[e]); grid y=64 covers
  // worst-case 8192 rows on one expert.
  gemm_bt<2><<<dim3(16, 64, 8), 256, 0, stream>>>(fn, w1t, M, 2048, 1024, act, nullptr, nullptr,
      counts, offsets, tok, nullptr);
  // MoE GEMM2: y2[pos][1024] = gate[pos] * (act[pos] @ w2[e]), K=2048
  gemm_bt<3><<<dim3(8, 64, 8), 256, 0, stream>>>(act, w2t, M, 1024, 2048, y2, nullptr, nullptr,
      counts, offsets, tok, gatel);

  final_add<<<M, 256, 0, stream>>>(hbuf, y2, inv, out);
}

// Round 10
// 350.630 us; speedup vs baseline: 2.7808x; 1.1274x over previous
//
// Transformer layer: RMSNorm→QKV→RoPE→SWA-GQA attn→wo+res→RMSNorm→top2 MoE→res
// Round 10: (1) MoE grid reordered (x=N,y=expert,z=Mtile) so working blocks
// form a contiguous dispatch prefix -> even CU fill; (2) QKV fused into one
// N=1536 GEMM vs stacked wqkvt; (3) rmsnorm2+router fused; (4) rope merged.
// B=2 S=2048 D=1024 H=16 HK=4 HD=64 WIN=1024 E=8 K=2 DH=2048
#include <hip/hip_runtime.h>
#include <hip/hip_bf16.h>

using bf16 = __hip_bfloat16;
typedef __attribute__((ext_vector_type(8))) short bf16x8;
typedef __attribute__((ext_vector_type(4))) short short4v;
typedef __attribute__((ext_vector_type(4))) float f32x4;

#define DEV static __device__ __forceinline__

DEV float b2f(bf16 v) { return __bfloat162float(v); }
DEV bf16  f2b(float f) { return __float2bfloat16(f); }
DEV short bbits(float f) { bf16 h = __float2bfloat16(f); short u; __builtin_memcpy(&u, &h, 2); return u; }
DEV float sb2f(short s) {
  unsigned u = ((unsigned)(unsigned short)s) << 16;
  float f; __builtin_memcpy(&f, &u, 4); return f;
}

// async global->LDS, 16B per lane, dest = wave-uniform base + lane*16
#define GL2LDS(g, l)                                                        \
  __builtin_amdgcn_global_load_lds(                                         \
      (const __attribute__((address_space(1))) void*)(g),                   \
      (__attribute__((address_space(3))) void*)(l), 16, 0, 0)

// ---------------------------------------------------------------------------
// Transpose + f32->bf16: src [K][N] f32 (batch z) -> dst [N][K] bf16
// ---------------------------------------------------------------------------
__global__ __launch_bounds__(256) void transpose_convert(
    const float* __restrict__ src, bf16* __restrict__ dst, int K, int N) {
  __shared__ float tile[64][65];
  int n0 = blockIdx.x * 64, k0 = blockIdx.y * 64;
  src += (size_t)blockIdx.z * K * N;
  dst += (size_t)blockIdx.z * K * N;
  int t = threadIdx.x;
  int rr = t >> 4, cc = (t & 15) * 4;
#pragma unroll
  for (int p = 0; p < 4; ++p) {
    int r = rr + p * 16;
    const float4 v = *(const float4*)&src[(size_t)(k0 + r) * N + n0 + cc];
    tile[r][cc] = v.x; tile[r][cc + 1] = v.y; tile[r][cc + 2] = v.z; tile[r][cc + 3] = v.w;
  }
  __syncthreads();
#pragma unroll
  for (int p = 0; p < 4; ++p) {
    int nr = rr + p * 16;
    short4v o;
    o[0] = bbits(tile[cc + 0][nr]);
    o[1] = bbits(tile[cc + 1][nr]);
    o[2] = bbits(tile[cc + 2][nr]);
    o[3] = bbits(tile[cc + 3][nr]);
    *(short4v*)&dst[(size_t)(n0 + nr) * K + k0 + cc] = o;
  }
}

// ---------------------------------------------------------------------------
// RMSNorm (attn norm): x f32 [rows][1024] -> bf16
// ---------------------------------------------------------------------------
__global__ __launch_bounds__(256) void rmsnorm_kernel(
    const float* __restrict__ x, const float* __restrict__ w,
    bf16* __restrict__ o, float eps) {
  int row = blockIdx.x;
  const float* xr = x + (size_t)row * 1024;
  int t = threadIdx.x;
  float4 v = *(const float4*)&xr[t * 4];
  float ss = v.x * v.x + v.y * v.y + v.z * v.z + v.w * v.w;
#pragma unroll
  for (int d = 32; d; d >>= 1) ss += __shfl_down(ss, d);
  __shared__ float red[4];
  if ((t & 63) == 0) red[t >> 6] = ss;
  __syncthreads();
  float sum = red[0] + red[1] + red[2] + red[3];
  float sc = rsqrtf(sum * (1.f / 1024.f) + eps);
  const float4 wv = *(const float4*)&w[t * 4];
  short4v pk;
  pk[0] = bbits(v.x * sc * wv.x);
  pk[1] = bbits(v.y * sc * wv.y);
  pk[2] = bbits(v.z * sc * wv.z);
  pk[3] = bbits(v.w * sc * wv.w);
  *(short4v*)&o[(size_t)row * 1024 + t * 4] = pk;
}

// ---------------------------------------------------------------------------
// rmsnorm2 + router fused: h f32 -> fn bf16, plus top-2 gates/eidx per row.
// ---------------------------------------------------------------------------
__global__ __launch_bounds__(256) void rmsnorm_router(
    const float* __restrict__ h, const float* __restrict__ w,
    const float* __restrict__ rw, bf16* __restrict__ fn,
    float* __restrict__ gates, int* __restrict__ eidx) {
  int row = blockIdx.x;
  const float* hr = h + (size_t)row * 1024;
  int t = threadIdx.x;
  float4 v = *(const float4*)&hr[t * 4];
  float ss = v.x * v.x + v.y * v.y + v.z * v.z + v.w * v.w;
#pragma unroll
  for (int d = 32; d; d >>= 1) ss += __shfl_down(ss, d);
  __shared__ float red[4];
  __shared__ float red2[4][8];
  if ((t & 63) == 0) red[t >> 6] = ss;
  __syncthreads();
  float sum = red[0] + red[1] + red[2] + red[3];
  float sc = rsqrtf(sum * (1.f / 1024.f) + 1e-6f);
  const float4 wv = *(const float4*)&w[t * 4];
  float f0 = v.x * sc * wv.x, f1 = v.y * sc * wv.y;
  float f2 = v.z * sc * wv.z, f3 = v.w * sc * wv.w;
  short4v pk;
  pk[0] = bbits(f0); pk[1] = bbits(f1); pk[2] = bbits(f2); pk[3] = bbits(f3);
  *(short4v*)&fn[(size_t)row * 1024 + t * 4] = pk;
  // router logits
  const float* rr = rw + (size_t)t * 4 * 8;
  float lg[8];
#pragma unroll
  for (int e = 0; e < 8; ++e)
    lg[e] = f0 * rr[e] + f1 * rr[8 + e] + f2 * rr[16 + e] + f3 * rr[24 + e];
#pragma unroll
  for (int d = 32; d; d >>= 1)
#pragma unroll
    for (int e = 0; e < 8; ++e) lg[e] += __shfl_down(lg[e], d);
  if ((t & 63) == 0)
#pragma unroll
    for (int e = 0; e < 8; ++e) red2[t >> 6][e] = lg[e];
  __syncthreads();
  if (t == 0) {
    float L[8];
#pragma unroll
    for (int e = 0; e < 8; ++e)
      L[e] = red2[0][e] + red2[1][e] + red2[2][e] + red2[3][e];
    int e0 = 0; float v0 = L[0];
#pragma unroll
    for (int e = 1; e < 8; ++e) if (L[e] > v0) { v0 = L[e]; e0 = e; }
    int e1 = -1; float v1 = -1e30f;
#pragma unroll
    for (int e = 0; e < 8; ++e) if (e != e0 && L[e] > v1) { v1 = L[e]; e1 = e; }
    float r1 = expf(v1 - v0);
    float den = 1.f + r1;
    gates[row * 2] = 1.f / den;
    gates[row * 2 + 1] = r1 / den;
    eidx[row * 2] = e0;
    eidx[row * 2 + 1] = e1;
  }
}

// ---------------------------------------------------------------------------
// RoPE merged (q then k). q: [4096][1024] (512 pairs/row); k: [4096][256].
// ---------------------------------------------------------------------------
__global__ __launch_bounds__(256) void rope_all(
    bf16* __restrict__ qb, bf16* __restrict__ kbuf,
    const float* __restrict__ fcos, const float* __restrict__ fsin) {
  int tid = blockIdx.x * 256 + threadIdx.x;
  bf16* p; int srow, i;
  if (tid < 2097152) {
    int row = tid >> 9, cp = tid & 511;
    p = qb + (size_t)row * 1024 + cp * 2;
    srow = row & 2047; i = cp & 31;
  } else {
    int t2 = tid - 2097152;
    int row = t2 >> 7, cp = t2 & 127;
    p = kbuf + (size_t)row * 256 + cp * 2;
    srow = row & 2047; i = cp & 31;
  }
  float t0 = b2f(p[0]), t1 = b2f(p[1]);
  float c = fcos[srow * 32 + i], sn = fsin[srow * 32 + i];
  p[0] = f2b(t0 * c - t1 * sn);
  p[1] = f2b(t0 * sn + t1 * c);
}

// ---------------------------------------------------------------------------
// GEMM C[M][N] = A[M][Kd] x Bt[N][Kd]^T   (bf16 in, f32 acc)
// 128x128 tile, BK=32, 4 waves, 2-phase dbuf. XCD swizzle for dense modes.
// MODE 1: f32 out = resid + acc (wo)
// MODE 2: MoE GEMM1 (gathered A via tok, silu, bf16 rows off+m); grid:
//         x=Ntile, y=expert, z=Mtile (working blocks contiguous in dispatch)
// MODE 3: MoE GEMM2 (contig A at off, K=2048, y2[off+m] = gate*acc); same grid
// MODE 5: fused QKV: N=1536 (q 0..1023 | k 1024..1279 | v 1280..1535->vt)
// ---------------------------------------------------------------------------
template <int MODE>
__global__ __launch_bounds__(256) void gemm_bt(
    const bf16* __restrict__ A, const bf16* __restrict__ Bt,
    int M, int N, int Kd,
    bf16* __restrict__ outb, bf16* __restrict__ outk, bf16* __restrict__ outv,
    float* __restrict__ outf, const float* __restrict__ resid,
    const int* __restrict__ counts, const int* __restrict__ offsets,
    const int* __restrict__ tok, const float* __restrict__ gatel) {
  int count = M, off = 0;
  const bf16* Ap = A;
  const bf16* Bp = Bt;
  int mb, nb;
  if (MODE == 2 || MODE == 3) {
    int e = blockIdx.y;
    count = counts[e]; off = offsets[e];
    Bp = Bt + (size_t)e * Kd * N;
    if (MODE == 3) Ap = A + (size_t)off * Kd;
    mb = blockIdx.z * 128; nb = blockIdx.x * 128;
  } else {
    int gx = gridDim.x;
    int flat = blockIdx.y * gx + blockIdx.x;
    int cpx = (gx * gridDim.y) >> 3;
    int swz = (flat & 7) * cpx + (flat >> 3);
    mb = (swz / gx) * 128; nb = (swz % gx) * 128;
  }
  if (mb >= count) return;

  __shared__ __align__(16) bf16 As[2][128 * 32];
  __shared__ __align__(16) bf16 Bs[2][128 * 32];

  int t = threadIdx.x;
  int lane = t & 63, wid = t >> 6;

  const bf16* agl[2];
  const bf16* bgl[2];
#pragma unroll
  for (int iss = 0; iss < 2; ++iss) {
    int p = iss * 256 + wid * 64 + lane;
    int row = p >> 2, cs = p & 3;
    int c = cs ^ (row & 3);
    int m = mb + row;
    const bf16* abase;
    if (MODE == 2) {
      int tokid = (m < count) ? tok[off + m] : 0;
      abase = A + (size_t)tokid * Kd;
    } else {
      int mm = (m < count) ? m : 0;
      abase = Ap + (size_t)mm * Kd;
    }
    agl[iss] = abase + c * 8;
    bgl[iss] = Bp + (size_t)(nb + row) * Kd + c * 8;
  }

  int wr = (wid >> 1) * 64, wc = (wid & 1) * 64;
  int lr = lane & 15, lkc = lane >> 4;

  auto stage = [&](int buf, int kt) {
#pragma unroll
    for (int iss = 0; iss < 2; ++iss) {
      GL2LDS(agl[iss] + kt * 32, &As[buf][(iss * 256 + wid * 64) * 8]);
      GL2LDS(bgl[iss] + kt * 32, &Bs[buf][(iss * 256 + wid * 64) * 8]);
    }
  };

  const f32x4 fzero = {0.f, 0.f, 0.f, 0.f};
  f32x4 acc[4][4];
#pragma unroll
  for (int i = 0; i < 4; ++i)
#pragma unroll
    for (int j = 0; j < 4; ++j) acc[i][j] = fzero;

  int nk = Kd >> 5;
  stage(0, 0);
  __syncthreads();
  for (int kt = 0; kt < nk; ++kt) {
    int cur = kt & 1;
    if (kt + 1 < nk) stage(cur ^ 1, kt + 1);
    bf16x8 af[4], bfr[4];
#pragma unroll
    for (int i = 0; i < 4; ++i) {
      int r = wr + i * 16 + lr;
      af[i] = *(const bf16x8*)&As[cur][r * 32 + ((lkc ^ (r & 3)) * 8)];
    }
#pragma unroll
    for (int j = 0; j < 4; ++j) {
      int r = wc + j * 16 + lr;
      bfr[j] = *(const bf16x8*)&Bs[cur][r * 32 + ((lkc ^ (r & 3)) * 8)];
    }
#pragma unroll
    for (int i = 0; i < 4; ++i)
#pragma unroll
      for (int j = 0; j < 4; ++j)
        acc[i][j] = __builtin_amdgcn_mfma_f32_16x16x32_bf16(af[i], bfr[j], acc[i][j], 0, 0, 0);
    __syncthreads();
  }

  int rq = lane >> 4;
#pragma unroll
  for (int i = 0; i < 4; ++i) {
#pragma unroll
    for (int j = 0; j < 4; ++j) {
      if (MODE == 5) {
        int n = nb + wc + j * 16 + lr;   // 0..1535; region uniform per (i,j)
        if (n >= 1280) {                 // v -> transposed vt
          int vcol = n - 1280;
          int kh = vcol >> 6, d = vcol & 63;
          int m0 = mb + wr + i * 16 + rq * 4;
          int bb = m0 >> 11, s = m0 & 2047;
          short4v pk;
#pragma unroll
          for (int r = 0; r < 4; ++r) pk[r] = bbits(acc[i][j][r]);
          *(short4v*)&outv[((size_t)((bb * 4 + kh) * 64 + d)) * 2048 + s] = pk;
        } else {
#pragma unroll
          for (int r = 0; r < 4; ++r) {
            int m = mb + wr + i * 16 + rq * 4 + r;
            float v = acc[i][j][r];
            if (n < 1024) outb[(size_t)m * 1024 + n] = f2b(v);
            else          outk[(size_t)m * 256 + (n - 1024)] = f2b(v);
          }
        }
      } else {
#pragma unroll
        for (int r = 0; r < 4; ++r) {
          int m = mb + wr + i * 16 + rq * 4 + r;
          int n = nb + wc + j * 16 + lr;
          float v = acc[i][j][r];
          if (MODE == 1) {
            outf[(size_t)m * N + n] = resid[(size_t)m * N + n] + v;
          } else if (MODE == 2) {
            if (m < count) {
              float sg = 1.f / (1.f + expf(-v));
              outb[(size_t)(off + m) * N + n] = f2b(v * sg);
            }
          } else if (MODE == 3) {
            if (m < count) {
              int row = off + m;
              outb[(size_t)row * N + n] = f2b(gatel[row] * v);
            }
          }
        }
      }
    }
  }
}

// ---------------------------------------------------------------------------
// Flash attention, sliding window 1024, GQA 16q/4kv heads, HD=64.
// ---------------------------------------------------------------------------
__global__ __launch_bounds__(256) void attn_kernel(
    const bf16* __restrict__ q, const bf16* __restrict__ kb,
    const bf16* __restrict__ vt, bf16* __restrict__ o) {
  int qb = blockIdx.x, h = blockIdx.y, b = blockIdx.z;
  int kh = h >> 2;
  int t = threadIdx.x;
  int lane = t & 63, wid = t >> 6;
  int lr = lane & 15, lkc = lane >> 4;
  int q0 = qb * 64;
  int qrow = q0 + wid * 16;

  __shared__ __align__(16) bf16 Ks[64 * 64];
  __shared__ __align__(16) bf16 Vs[64 * 64];   // [dim][key]
  __shared__ __align__(16) bf16 Ps[4][16 * 72];

  bf16x8 aq[2];
#pragma unroll
  for (int kk = 0; kk < 2; ++kk)
    aq[kk] = *(const bf16x8*)&q[(size_t)(b * 2048 + qrow + lr) * 1024 + h * 64 + kk * 32 + lkc * 8];

  const f32x4 fzero = {0.f, 0.f, 0.f, 0.f};
  f32x4 oacc[4];
  float mrun[4], lrun[4];
#pragma unroll
  for (int r = 0; r < 4; ++r) { oacc[r] = fzero; mrun[r] = -1e30f; lrun[r] = 0.f; }

  int klo = q0 - 1023; if (klo < 0) klo = 0;
  int tlo = klo >> 6, thi = q0 >> 6;
  int skey = t >> 3;    // 0..31
  int sch = t & 7;      // logical 16B chunk

  for (int kt = tlo; kt <= thi; ++kt) {
    int kbase = kt * 64;
#pragma unroll
    for (int pp = 0; pp < 2; ++pp) {
      int key = skey + pp * 32;
      bf16x8 kv = *(const bf16x8*)&kb[(size_t)(b * 2048 + kbase + key) * 256 + kh * 64 + sch * 8];
      *(bf16x8*)&Ks[key * 64 + ((sch ^ (key & 7)) * 8)] = kv;
      bf16x8 vv = *(const bf16x8*)&vt[((size_t)((b * 4 + kh) * 64 + key)) * 2048 + kbase + sch * 8];
      *(bf16x8*)&Vs[key * 64 + ((sch ^ (key & 7)) * 8)] = vv;
    }
    __syncthreads();

    f32x4 sacc[4];
#pragma unroll
    for (int nt = 0; nt < 4; ++nt) sacc[nt] = fzero;
#pragma unroll
    for (int nt = 0; nt < 4; ++nt)
#pragma unroll
      for (int kk = 0; kk < 2; ++kk) {
        int r = nt * 16 + lr;
        bf16x8 bk = *(const bf16x8*)&Ks[r * 64 + (((kk * 4 + lkc) ^ (r & 7)) * 8)];
        sacc[nt] = __builtin_amdgcn_mfma_f32_16x16x32_bf16(aq[kk], bk, sacc[nt], 0, 0, 0);
      }

    float sval[4][4], mt[4];
    int qg = qrow + lkc * 4;
#pragma unroll
    for (int r = 0; r < 4; ++r) mt[r] = -1e30f;
#pragma unroll
    for (int nt = 0; nt < 4; ++nt) {
      int kkey = kbase + nt * 16 + lr;
#pragma unroll
      for (int r = 0; r < 4; ++r) {
        float s = sacc[nt][r] * 0.125f;
        int qq = qg + r;
        bool valid = (kkey <= qq) && (qq - kkey < 1024);
        s = valid ? s : -1e30f;
        sval[nt][r] = s;
        mt[r] = fmaxf(mt[r], s);
      }
    }
#pragma unroll
    for (int d = 1; d < 16; d <<= 1)
#pragma unroll
      for (int r = 0; r < 4; ++r) mt[r] = fmaxf(mt[r], __shfl_xor(mt[r], d));
    float alpha[4], rs[4];
#pragma unroll
    for (int r = 0; r < 4; ++r) {
      float mn = fmaxf(mrun[r], mt[r]);
      alpha[r] = __expf(mrun[r] - mn);
      mrun[r] = mn;
      rs[r] = 0.f;
    }
#pragma unroll
    for (int nt = 0; nt < 4; ++nt)
#pragma unroll
      for (int r = 0; r < 4; ++r) {
        float pv = __expf(sval[nt][r] - mrun[r]);
        sval[nt][r] = pv;
        rs[r] += pv;
      }
#pragma unroll
    for (int d = 1; d < 16; d <<= 1)
#pragma unroll
      for (int r = 0; r < 4; ++r) rs[r] += __shfl_xor(rs[r], d);
#pragma unroll
    for (int r = 0; r < 4; ++r) lrun[r] = lrun[r] * alpha[r] + rs[r];
#pragma unroll
    for (int dt = 0; dt < 4; ++dt) {
      f32x4 t4 = oacc[dt];
#pragma unroll
      for (int r = 0; r < 4; ++r) t4[r] *= alpha[r];
      oacc[dt] = t4;
    }

    bf16* pw = &Ps[wid][0];
#pragma unroll
    for (int nt = 0; nt < 4; ++nt)
#pragma unroll
      for (int r = 0; r < 4; ++r)
        pw[(lkc * 4 + r) * 72 + nt * 16 + lr] = f2b(sval[nt][r]);
    __syncthreads();

    bf16x8 pa[2];
#pragma unroll
    for (int kk2 = 0; kk2 < 2; ++kk2)
      pa[kk2] = *(const bf16x8*)&pw[lr * 72 + kk2 * 32 + lkc * 8];
#pragma unroll
    for (int dt = 0; dt < 4; ++dt)
#pragma unroll
      for (int kk2 = 0; kk2 < 2; ++kk2) {
        int rrow = dt * 16 + lr;
        bf16x8 bv = *(const bf16x8*)&Vs[rrow * 64 + (((kk2 * 4 + lkc) ^ (rrow & 7)) * 8)];
        oacc[dt] = __builtin_amdgcn_mfma_f32_16x16x32_bf16(pa[kk2], bv, oacc[dt], 0, 0, 0);
      }
    __syncthreads();
  }

#pragma unroll
  for (int dt = 0; dt < 4; ++dt)
#pragma unroll
    for (int r = 0; r < 4; ++r) {
      int qq = qrow + lkc * 4 + r;
      int dd = dt * 16 + lr;
      o[(size_t)(b * 2048 + qq) * 1024 + h * 64 + dd] = f2b(oacc[dt][r] / lrun[r]);
    }
}

// ---------------------------------------------------------------------------
// moe_setup: 1 block, 1024 threads. LDS histogram -> scan -> fill (+inv map).
// ---------------------------------------------------------------------------
__global__ __launch_bounds__(1024) void moe_setup(
    const int* __restrict__ eidx, const float* __restrict__ gates,
    int* __restrict__ counts, int* __restrict__ offsets,
    int* __restrict__ tok, float* __restrict__ gatel, int* __restrict__ inv) {
  __shared__ int hist[8];
  __shared__ int cur[8];
  int t = threadIdx.x;
  if (t < 8) hist[t] = 0;
  __syncthreads();
  int e[8];
#pragma unroll
  for (int c = 0; c < 8; ++c) {
    e[c] = eidx[c * 1024 + t];
    atomicAdd(&hist[e[c]], 1);
  }
  __syncthreads();
  if (t == 0) {
    int o = 0;
#pragma unroll
    for (int i = 0; i < 8; ++i) {
      offsets[i] = o; cur[i] = o;
      int cnt = hist[i]; counts[i] = cnt; o += cnt;
    }
  }
  __syncthreads();
#pragma unroll
  for (int c = 0; c < 8; ++c) {
    int i = c * 1024 + t;
    int pos = atomicAdd(&cur[e[c]], 1);
    tok[pos] = i >> 1;
    gatel[pos] = gates[i];
    inv[i] = pos;
  }
}

// final: out[t] = h[t] + y2[inv[2t]] + y2[inv[2t+1]]  (y2 rows already gated)
__global__ __launch_bounds__(256) void final_add(
    const float* __restrict__ h, const bf16* __restrict__ y2,
    const int* __restrict__ inv, float* __restrict__ out) {
  int tokid = blockIdx.x;
  int t = threadIdx.x;
  int i0 = inv[tokid * 2], i1 = inv[tokid * 2 + 1];
  size_t base = (size_t)tokid * 1024 + t * 4;
  float4 a = *(const float4*)&h[base];
  short4v p0 = *(const short4v*)&y2[(size_t)i0 * 1024 + t * 4];
  short4v p1 = *(const short4v*)&y2[(size_t)i1 * 1024 + t * 4];
  float4 o;
  o.x = a.x + sb2f(p0[0]) + sb2f(p1[0]);
  o.y = a.y + sb2f(p0[1]) + sb2f(p1[1]);
  o.z = a.z + sb2f(p0[2]) + sb2f(p1[2]);
  o.w = a.w + sb2f(p0[3]) + sb2f(p1[3]);
  *(float4*)&out[base] = o;
}

// ---------------------------------------------------------------------------
extern "C" void kernel_launch(void* const* d_in, const int* in_sizes, int n_in,
                              void* d_out, int out_size, void* d_ws, size_t ws_size,
                              hipStream_t stream) {
  const float* x    = (const float*)d_in[0];
  const float* fcos = (const float*)d_in[1];
  const float* fsin = (const float*)d_in[2];
  const float* attw = (const float*)d_in[3];
  const float* wq   = (const float*)d_in[4];
  const float* wk   = (const float*)d_in[5];
  const float* wv   = (const float*)d_in[6];
  const float* wo   = (const float*)d_in[7];
  const float* ffnw = (const float*)d_in[8];
  const float* rw   = (const float*)d_in[9];
  const float* w1   = (const float*)d_in[10];
  const float* w2   = (const float*)d_in[11];
  float* out = (float*)d_out;

  const int M = 4096;  // B*S tokens
  char* p = (char*)d_ws;
  auto alloc = [&](size_t b) { char* r = p; p += (b + 255) & ~(size_t)255; return r; };

  bf16* hn     = (bf16*)alloc((size_t)M * 1024 * 2);
  bf16* qb     = (bf16*)alloc((size_t)M * 1024 * 2);
  bf16* kbuf   = (bf16*)alloc((size_t)M * 256 * 2);
  bf16* vt     = (bf16*)alloc((size_t)M * 256 * 2);
  bf16* ob     = (bf16*)alloc((size_t)M * 1024 * 2);
  float* hbuf  = (float*)alloc((size_t)M * 1024 * 4);
  bf16* fn     = (bf16*)alloc((size_t)M * 1024 * 2);
  bf16* wqkvt  = (bf16*)alloc((size_t)1536 * 1024 * 2);
  bf16* wot    = (bf16*)alloc((size_t)1024 * 1024 * 2);
  bf16* w1t    = (bf16*)alloc((size_t)8 * 2048 * 1024 * 2);
  bf16* w2t    = (bf16*)alloc((size_t)8 * 1024 * 2048 * 2);
  bf16* act    = (bf16*)alloc((size_t)8192 * 2048 * 2);
  bf16* y2     = (bf16*)alloc((size_t)8192 * 1024 * 2);
  float* gates = (float*)alloc((size_t)M * 2 * 4);
  int* eidx    = (int*)alloc((size_t)M * 2 * 4);
  int* counts  = (int*)alloc(8 * 4);
  int* offsets = (int*)alloc(8 * 4);
  int* tok     = (int*)alloc(8192 * 4);
  int* inv     = (int*)alloc(8192 * 4);
  float* gatel = (float*)alloc(8192 * 4);

  // weight transposes (f32 -> bf16 [N][K]); q/k/v stacked into wqkvt
  transpose_convert<<<dim3(16, 16, 1), 256, 0, stream>>>(wq, wqkvt, 1024, 1024);
  transpose_convert<<<dim3(4, 16, 1), 256, 0, stream>>>(wk, wqkvt + (size_t)1024 * 1024, 1024, 256);
  transpose_convert<<<dim3(4, 16, 1), 256, 0, stream>>>(wv, wqkvt + (size_t)1280 * 1024, 1024, 256);
  transpose_convert<<<dim3(16, 16, 1), 256, 0, stream>>>(wo, wot, 1024, 1024);
  transpose_convert<<<dim3(32, 16, 8), 256, 0, stream>>>(w1, w1t, 1024, 2048);
  transpose_convert<<<dim3(16, 32, 8), 256, 0, stream>>>(w2, w2t, 2048, 1024);

  rmsnorm_kernel<<<M, 256, 0, stream>>>(x, attw, hn, 1e-5f);

  // fused QKV GEMM: N=1536
  gemm_bt<5><<<dim3(12, 32, 1), 256, 0, stream>>>(hn, wqkvt, M, 1536, 1024,
      qb, kbuf, vt, nullptr, nullptr, nullptr, nullptr, nullptr, nullptr);

  rope_all<<<10240, 256, 0, stream>>>(qb, kbuf, fcos, fsin);

  attn_kernel<<<dim3(32, 16, 2), 256, 0, stream>>>(qb, kbuf, vt, ob);

  gemm_bt<1><<<dim3(8, 32, 1), 256, 0, stream>>>(ob, wot, M, 1024, 1024,
      nullptr, nullptr, nullptr, hbuf, x, nullptr, nullptr, nullptr, nullptr);

  rmsnorm_router<<<M, 256, 0, stream>>>(hbuf, ffnw, rw, fn, gates, eidx);
  moe_setup<<<1, 1024, 0, stream>>>(eidx, gates, counts, offsets, tok, gatel, inv);

  // MoE GEMM1: grid (Ntile, expert, Mtile) -> working blocks are a contiguous
  // dispatch prefix (z small for all experts simultaneously).
  gemm_bt<2><<<dim3(16, 8, 64), 256, 0, stream>>>(fn, w1t, M, 2048, 1024,
      act, nullptr, nullptr, nullptr, nullptr, counts, offsets, tok, nullptr);
  // MoE GEMM2: y2[pos][1024] = gate[pos] * (act[pos] @ w2[e]), K=2048
  gemm_bt<3><<<dim3(8, 8, 64), 256, 0, stream>>>(act, w2t, M, 1024, 2048,
      y2, nullptr, nullptr, nullptr, nullptr, counts, offsets, tok, gatel);

  final_add<<<M, 256, 0, stream>>>(hbuf, y2, inv, out);
}